// Round 17
// baseline (71.414 us; speedup 1.0000x reference)
//
#include <hip/hip_runtime.h>
#include <hip/hip_bf16.h>
#include <stdint.h>

#define TOKENS 4096
#define DIN 1024
#define DOUT 1024
#define RANK 8
#define BM 128
#define BN 64
#define BK 64

typedef __attribute__((ext_vector_type(4))) float f32x4;
typedef __attribute__((ext_vector_type(8))) short short8;

__device__ __forceinline__ unsigned short f2bf(float f) {
    union { float f; unsigned u; } v; v.f = f;
    unsigned r = v.u + 0x7FFFu + ((v.u >> 16) & 1u);
    return (unsigned short)(r >> 16);
}

__device__ __forceinline__ float dot4v(f32x4 a, f32x4 b) {
    return a.x * b.x + a.y * b.y + a.z * b.z + a.w * b.w;
}

// R15-proven inter kernel: 2 tokens/block, each token split across TWO
// half-token waves (8192 waves -> ~22/CU, 18 indep float4 in flight each).
// B-stream loads are NON-TEMPORAL (single-use 128 MB — don't thrash L2).
// Blocks [2048,2304): W fp32->bf16.
__global__ __launch_bounds__(256) void k_inter_cvt(const float* __restrict__ x,
                                                   const float* __restrict__ Bp,
                                                   const float* __restrict__ W,
                                                   float* __restrict__ inter,
                                                   ushort* __restrict__ xb,
                                                   ushort* __restrict__ Wb) {
    const int bid = blockIdx.x;
    const int tid = threadIdx.x;

    if (bid >= 2048) {
        const int b2 = bid - 2048;
        const f32x4* w4 = (const f32x4*)(W + (size_t)b2 * 4096);
        ushort4* o4 = (ushort4*)(Wb + (size_t)b2 * 4096);
#pragma unroll
        for (int j = 0; j < 4; ++j) {
            f32x4 v = w4[j * 256 + tid];
            ushort4 u;
            u.x = f2bf(v.x); u.y = f2bf(v.y); u.z = f2bf(v.z); u.w = f2bf(v.w);
            o4[j * 256 + tid] = u;
        }
        return;
    }

    const int lane = tid & 63, wave = tid >> 6;
    const int t = bid * 2 + (wave >> 1);     // token
    const int h = wave & 1;                  // half: elements [h*512, h*512+512)

    // ---- x half -> regs + xb (coalesced f4) ----
    const f32x4* x4 = (const f32x4*)(x + (size_t)t * DIN);
    f32x4 xv0 = x4[h * 128 + lane];
    f32x4 xv1 = x4[h * 128 + 64 + lane];

    ushort4* xb4 = (ushort4*)(xb + (size_t)t * DIN);
    {
        ushort4 u0, u1;
        u0.x = f2bf(xv0.x); u0.y = f2bf(xv0.y); u0.z = f2bf(xv0.z); u0.w = f2bf(xv0.w);
        u1.x = f2bf(xv1.x); u1.y = f2bf(xv1.y); u1.z = f2bf(xv1.z); u1.w = f2bf(xv1.w);
        xb4[h * 128 + lane] = u0;
        xb4[h * 128 + 64 + lane] = u1;
    }

    // ---- B half-rows: issue all 16 NT loads, then dot (max in-flight) ----
    const f32x4* B4 = (const f32x4*)(Bp + (size_t)t * RANK * DIN);
    f32x4 bv[RANK][2];
#pragma unroll
    for (int r = 0; r < RANK; ++r) {
        bv[r][0] = __builtin_nontemporal_load(&B4[r * 256 + h * 128 + lane]);
        bv[r][1] = __builtin_nontemporal_load(&B4[r * 256 + h * 128 + 64 + lane]);
    }

    float acc[RANK];
#pragma unroll
    for (int r = 0; r < RANK; ++r)
        acc[r] = dot4v(bv[r][0], xv0) + dot4v(bv[r][1], xv1);

#pragma unroll
    for (int r = 0; r < RANK; ++r) {
#pragma unroll
        for (int off = 32; off > 0; off >>= 1)
            acc[r] += __shfl_xor(acc[r], off, 64);
    }

    __shared__ float part[4][RANK];
    if (lane == 0) {
#pragma unroll
        for (int r = 0; r < RANK; ++r) part[wave][r] = acc[r];
    }
    __syncthreads();

    if ((wave == 0 || wave == 1) && lane < RANK) {
        const int tk = bid * 2 + wave;
        inter[(size_t)tk * RANK + lane] =
            part[wave * 2][lane] + part[wave * 2 + 1][lane];
    }
}

// out[m,o] = bias[o] + Xb@Wb^T (bf16 MFMA) + sum_r inter[m,r]*A[m,o,r]
// R14/R15 structure (counted-vmcnt order-pinned pipeline + T2 swizzle).
// A-stream loads NT (single-use); out stores NT (never re-read).
__global__ __launch_bounds__(256, 2) void k_gemm_fused(const ushort* __restrict__ Xb,
                                                       const ushort* __restrict__ Wb,
                                                       const float* __restrict__ bias,
                                                       const float* __restrict__ inter,
                                                       const float* __restrict__ Ap,
                                                       float* __restrict__ out) {
    __shared__ ushort As[2][BM * BK];   // 2 x 16 KB
    __shared__ ushort Bs[2][BN * BK];   // 2 x 8 KB
    __shared__ float sInter[BM * 8];    // 4 KB
    __shared__ float sBias[BN];

    const int tid = threadIdx.x;
    const int lane = tid & 63, wave = tid >> 6;
    const int wm = wave >> 1, wn = wave & 1;

    const int bid = blockIdx.x;
    const int swz = (bid & 7) * 64 + (bid >> 3);
    const int M0 = (swz >> 4) * BM;
    const int N0 = (swz & 15) * BN;

    const int col16 = lane & 15;
    const int kg = lane >> 4;
    const int c8 = col16 & 7;

    ((float4*)sInter)[tid] = ((const float4*)(inter + (size_t)M0 * RANK))[tid];
    if (tid < 16) ((float4*)sBias)[tid] = ((const float4*)(bias + N0))[tid];

    const float* Abase = Ap + ((size_t)(M0 + wm * 64 + kg * 4) * DOUT +
                               (N0 + wn * 32 + col16)) * RANK;

    auto stage = [&](int b, int kt) {
#pragma unroll
        for (int st = 0; st < 4; ++st) {
            int flat = st * 256 + tid;
            int row = flat >> 3, ch = flat & 7;
            int chs = ch ^ (row & 7);
            const ushort* g = Xb + (size_t)(M0 + row) * DIN + kt + chs * 8;
            __builtin_amdgcn_global_load_lds(
                (const __attribute__((address_space(1))) void*)g,
                (__attribute__((address_space(3))) void*)(&As[b][flat * 8]), 16, 0, 0);
        }
#pragma unroll
        for (int st = 0; st < 2; ++st) {
            int flat = st * 256 + tid;
            int row = flat >> 3, ch = flat & 7;
            int chs = ch ^ (row & 7);
            const ushort* g = Wb + (size_t)(N0 + row) * DIN + kt + chs * 8;
            __builtin_amdgcn_global_load_lds(
                (const __attribute__((address_space(1))) void*)g,
                (__attribute__((address_space(3))) void*)(&Bs[b][flat * 8]), 16, 0, 0);
        }
    };

    auto aptr = [&](int e) {
        const int nf = e >> 3, mf = (e >> 1) & 3, rg0 = (e & 1) * 2;
        return Abase + ((size_t)(mf * 16 + rg0) * DOUT + nf * 16) * RANK;
    };

    f32x4 areg[2][4];

    {
        const f32x4* Ae0 = (const f32x4*)aptr(0);
        const f32x4* Ae1 = (const f32x4*)(aptr(0) + (size_t)DOUT * RANK);
        areg[0][0] = __builtin_nontemporal_load(&Ae0[0]);
        areg[0][1] = __builtin_nontemporal_load(&Ae0[1]);
        areg[0][2] = __builtin_nontemporal_load(&Ae1[0]);
        areg[0][3] = __builtin_nontemporal_load(&Ae1[1]);
    }
    __builtin_amdgcn_sched_barrier(0);
    stage(0, 0);

    f32x4 acc[4][2] = {};

#pragma unroll
    for (int t = 0; t < 16; ++t) {
        const int cur = t & 1;

        if (t < 15) {
            const f32x4* Ae0 = (const f32x4*)aptr(t + 1);
            const f32x4* Ae1 = (const f32x4*)(aptr(t + 1) + (size_t)DOUT * RANK);
            areg[cur ^ 1][0] = __builtin_nontemporal_load(&Ae0[0]);
            areg[cur ^ 1][1] = __builtin_nontemporal_load(&Ae0[1]);
            areg[cur ^ 1][2] = __builtin_nontemporal_load(&Ae1[0]);
            areg[cur ^ 1][3] = __builtin_nontemporal_load(&Ae1[1]);
            __builtin_amdgcn_sched_barrier(0);
            stage(cur ^ 1, (t + 1) * BK);
        }

        if (t == 0) {
            asm volatile("s_waitcnt vmcnt(10) lgkmcnt(0)" ::: "memory");
        } else if (t < 15) {
            asm volatile("s_waitcnt vmcnt(10)" ::: "memory");
        } else {
            asm volatile("s_waitcnt vmcnt(0)" ::: "memory");
        }
        __builtin_amdgcn_s_barrier();

#pragma unroll
        for (int ks = 0; ks < 2; ++ks) {
            short8 a[4], b[2];
#pragma unroll
            for (int m4 = 0; m4 < 4; ++m4) {
                const int chs = (ks * 4 + kg) ^ c8;
                a[m4] = *(const short8*)(&As[cur][(wm * 64 + m4 * 16 + col16) * BK + chs * 8]);
            }
#pragma unroll
            for (int n2 = 0; n2 < 2; ++n2) {
                const int chs = (ks * 4 + kg) ^ c8;
                b[n2] = *(const short8*)(&Bs[cur][(wn * 32 + n2 * 16 + col16) * BK + chs * 8]);
            }
#pragma unroll
            for (int m4 = 0; m4 < 4; ++m4)
#pragma unroll
                for (int n2 = 0; n2 < 2; ++n2)
                    acc[m4][n2] = __builtin_amdgcn_mfma_f32_16x16x32_bf16(
                        a[m4], b[n2], acc[m4][n2], 0, 0, 0);
        }

        {
            const int nf = t >> 3, mf = (t >> 1) & 3, rg0 = (t & 1) * 2;
            const int mloc0 = wm * 64 + mf * 16 + kg * 4 + rg0;
            const f32x4* iv0 = (const f32x4*)(sInter + mloc0 * 8);
            const f32x4* iv1 = (const f32x4*)(sInter + (mloc0 + 1) * 8);
            f32x4 i00 = iv0[0], i01 = iv0[1], i10 = iv1[0], i11 = iv1[1];
            float d0 = dot4v(areg[cur][0], i00) + dot4v(areg[cur][1], i01);
            float d1 = dot4v(areg[cur][2], i10) + dot4v(areg[cur][3], i11);
            acc[mf][nf][rg0] += d0;
            acc[mf][nf][rg0 + 1] += d1;
        }

        __builtin_amdgcn_s_barrier();
    }

#pragma unroll
    for (int nf = 0; nf < 2; ++nf) {
        const int oc = wn * 32 + nf * 16 + col16;
        const int o = N0 + oc;
        const float bb = sBias[oc];
#pragma unroll
        for (int mf = 0; mf < 4; ++mf) {
#pragma unroll
            for (int rg = 0; rg < 4; ++rg) {
                const int m = M0 + wm * 64 + mf * 16 + kg * 4 + rg;
                __builtin_nontemporal_store(acc[mf][nf][rg] + bb,
                                            &out[(size_t)m * DOUT + o]);
            }
        }
    }
}

extern "C" void kernel_launch(void* const* d_in, const int* in_sizes, int n_in,
                              void* d_out, int out_size, void* d_ws, size_t ws_size,
                              hipStream_t stream) {
    const float* x    = (const float*)d_in[0];
    const float* Ap   = (const float*)d_in[1];
    const float* Bp   = (const float*)d_in[2];
    const float* W    = (const float*)d_in[3];
    const float* bias = (const float*)d_in[4];
    float* out = (float*)d_out;

    // ws: xb (8 MB) | Wb (2 MB) | inter (128 KB)
    ushort* xb = (ushort*)d_ws;
    ushort* Wb = xb + (size_t)TOKENS * DIN;
    float* inter = (float*)(Wb + (size_t)DOUT * DIN);

    hipLaunchKernelGGL(k_inter_cvt, dim3(2048 + 256), dim3(256), 0, stream,
                       x, Bp, W, inter, xb, Wb);
    hipLaunchKernelGGL(k_gemm_fused, dim3((TOKENS / BM) * (DOUT / BN)), dim3(256), 0, stream,
                       xb, Wb, bias, inter, Ap, out);
}

// Round 18
// 67.508 us; speedup vs baseline: 1.0579x; 1.0579x over previous
//
#include <hip/hip_runtime.h>
#include <hip/hip_bf16.h>
#include <stdint.h>

#define TOKENS 4096
#define DIN 1024
#define DOUT 1024
#define RANK 8
#define BM 128
#define BN 64
#define BK 64

typedef __attribute__((ext_vector_type(4))) float f32x4;
typedef __attribute__((ext_vector_type(8))) short short8;

__device__ __forceinline__ unsigned short f2bf(float f) {
    union { float f; unsigned u; } v; v.f = f;
    unsigned r = v.u + 0x7FFFu + ((v.u >> 16) & 1u);
    return (unsigned short)(r >> 16);
}

__device__ __forceinline__ float dot4(float4 a, float4 b) {
    return a.x * b.x + a.y * b.y + a.z * b.z + a.w * b.w;
}

// R15-proven inter kernel: 2 tokens/block, each token split across TWO
// half-token waves (8192 waves -> ~22/CU, 18 indep float4 in flight each).
// Blocks [2048,2304): W fp32->bf16.
__global__ __launch_bounds__(256) void k_inter_cvt(const float* __restrict__ x,
                                                   const float* __restrict__ Bp,
                                                   const float* __restrict__ W,
                                                   float* __restrict__ inter,
                                                   ushort* __restrict__ xb,
                                                   ushort* __restrict__ Wb) {
    const int bid = blockIdx.x;
    const int tid = threadIdx.x;

    if (bid >= 2048) {
        const int b2 = bid - 2048;
        const float4* w4 = (const float4*)(W + (size_t)b2 * 4096);
        ushort4* o4 = (ushort4*)(Wb + (size_t)b2 * 4096);
#pragma unroll
        for (int j = 0; j < 4; ++j) {
            float4 v = w4[j * 256 + tid];
            ushort4 u;
            u.x = f2bf(v.x); u.y = f2bf(v.y); u.z = f2bf(v.z); u.w = f2bf(v.w);
            o4[j * 256 + tid] = u;
        }
        return;
    }

    const int lane = tid & 63, wave = tid >> 6;
    const int t = bid * 2 + (wave >> 1);     // token
    const int h = wave & 1;                  // half: elements [h*512, h*512+512)

    // ---- x half -> regs + xb (coalesced f4) ----
    const float4* x4 = (const float4*)(x + (size_t)t * DIN);
    float4 xv0 = x4[h * 128 + lane];
    float4 xv1 = x4[h * 128 + 64 + lane];

    ushort4* xb4 = (ushort4*)(xb + (size_t)t * DIN);
    {
        ushort4 u0, u1;
        u0.x = f2bf(xv0.x); u0.y = f2bf(xv0.y); u0.z = f2bf(xv0.z); u0.w = f2bf(xv0.w);
        u1.x = f2bf(xv1.x); u1.y = f2bf(xv1.y); u1.z = f2bf(xv1.z); u1.w = f2bf(xv1.w);
        xb4[h * 128 + lane] = u0;
        xb4[h * 128 + 64 + lane] = u1;
    }

    // ---- B half-rows: issue all 16 loads, then dot (max in-flight) ----
    const float4* B4 = (const float4*)(Bp + (size_t)t * RANK * DIN);
    float4 bv[RANK][2];
#pragma unroll
    for (int r = 0; r < RANK; ++r) {
        bv[r][0] = B4[r * 256 + h * 128 + lane];
        bv[r][1] = B4[r * 256 + h * 128 + 64 + lane];
    }

    float acc[RANK];
#pragma unroll
    for (int r = 0; r < RANK; ++r)
        acc[r] = dot4(bv[r][0], xv0) + dot4(bv[r][1], xv1);

#pragma unroll
    for (int r = 0; r < RANK; ++r) {
#pragma unroll
        for (int off = 32; off > 0; off >>= 1)
            acc[r] += __shfl_xor(acc[r], off, 64);
    }

    __shared__ float part[4][RANK];
    if (lane == 0) {
#pragma unroll
        for (int r = 0; r < RANK; ++r) part[wave][r] = acc[r];
    }
    __syncthreads();

    // wave0 lanes 0..7 -> token t0; wave1 lanes 0..7 -> token t1
    if ((wave == 0 || wave == 1) && lane < RANK) {
        const int tk = bid * 2 + wave;
        inter[(size_t)tk * RANK + lane] =
            part[wave * 2][lane] + part[wave * 2 + 1][lane];
    }
}

// out[m,o] = bias[o] + Xb@Wb^T (bf16 MFMA) + sum_r inter[m,r]*A[m,o,r]
// R14/R15 structure (counted-vmcnt order-pinned pipeline + T2 swizzle).
__global__ __launch_bounds__(256, 2) void k_gemm_fused(const ushort* __restrict__ Xb,
                                                       const ushort* __restrict__ Wb,
                                                       const float* __restrict__ bias,
                                                       const float* __restrict__ inter,
                                                       const float* __restrict__ Ap,
                                                       float* __restrict__ out) {
    __shared__ ushort As[2][BM * BK];   // 2 x 16 KB
    __shared__ ushort Bs[2][BN * BK];   // 2 x 8 KB
    __shared__ float sInter[BM * 8];    // 4 KB
    __shared__ float sBias[BN];

    const int tid = threadIdx.x;
    const int lane = tid & 63, wave = tid >> 6;
    const int wm = wave >> 1, wn = wave & 1;

    const int bid = blockIdx.x;
    const int swz = (bid & 7) * 64 + (bid >> 3);
    const int M0 = (swz >> 4) * BM;
    const int N0 = (swz & 15) * BN;

    const int col16 = lane & 15;
    const int kg = lane >> 4;
    const int c8 = col16 & 7;

    ((float4*)sInter)[tid] = ((const float4*)(inter + (size_t)M0 * RANK))[tid];
    if (tid < 16) ((float4*)sBias)[tid] = ((const float4*)(bias + N0))[tid];

    const float* Abase = Ap + ((size_t)(M0 + wm * 64 + kg * 4) * DOUT +
                               (N0 + wn * 32 + col16)) * RANK;

    auto stage = [&](int b, int kt) {
#pragma unroll
        for (int st = 0; st < 4; ++st) {
            int flat = st * 256 + tid;
            int row = flat >> 3, ch = flat & 7;
            int chs = ch ^ (row & 7);
            const ushort* g = Xb + (size_t)(M0 + row) * DIN + kt + chs * 8;
            __builtin_amdgcn_global_load_lds(
                (const __attribute__((address_space(1))) void*)g,
                (__attribute__((address_space(3))) void*)(&As[b][flat * 8]), 16, 0, 0);
        }
#pragma unroll
        for (int st = 0; st < 2; ++st) {
            int flat = st * 256 + tid;
            int row = flat >> 3, ch = flat & 7;
            int chs = ch ^ (row & 7);
            const ushort* g = Wb + (size_t)(N0 + row) * DIN + kt + chs * 8;
            __builtin_amdgcn_global_load_lds(
                (const __attribute__((address_space(1))) void*)g,
                (__attribute__((address_space(3))) void*)(&Bs[b][flat * 8]), 16, 0, 0);
        }
    };

    auto aptr = [&](int e) {
        const int nf = e >> 3, mf = (e >> 1) & 3, rg0 = (e & 1) * 2;
        return Abase + ((size_t)(mf * 16 + rg0) * DOUT + nf * 16) * RANK;
    };

    float4 areg[2][4];

    {
        const float* Ae0 = aptr(0);
        areg[0][0] = ((const float4*)Ae0)[0];
        areg[0][1] = ((const float4*)Ae0)[1];
        areg[0][2] = ((const float4*)(Ae0 + (size_t)DOUT * RANK))[0];
        areg[0][3] = ((const float4*)(Ae0 + (size_t)DOUT * RANK))[1];
    }
    __builtin_amdgcn_sched_barrier(0);
    stage(0, 0);

    f32x4 acc[4][2] = {};

#pragma unroll
    for (int t = 0; t < 16; ++t) {
        const int cur = t & 1;

        if (t < 15) {
            const float* Ae0 = aptr(t + 1);
            areg[cur ^ 1][0] = ((const float4*)Ae0)[0];
            areg[cur ^ 1][1] = ((const float4*)Ae0)[1];
            areg[cur ^ 1][2] = ((const float4*)(Ae0 + (size_t)DOUT * RANK))[0];
            areg[cur ^ 1][3] = ((const float4*)(Ae0 + (size_t)DOUT * RANK))[1];
            __builtin_amdgcn_sched_barrier(0);
            stage(cur ^ 1, (t + 1) * BK);
        }

        if (t == 0) {
            asm volatile("s_waitcnt vmcnt(10) lgkmcnt(0)" ::: "memory");
        } else if (t < 15) {
            asm volatile("s_waitcnt vmcnt(10)" ::: "memory");
        } else {
            asm volatile("s_waitcnt vmcnt(0)" ::: "memory");
        }
        __builtin_amdgcn_s_barrier();

#pragma unroll
        for (int ks = 0; ks < 2; ++ks) {
            short8 a[4], b[2];
#pragma unroll
            for (int m4 = 0; m4 < 4; ++m4) {
                const int chs = (ks * 4 + kg) ^ c8;
                a[m4] = *(const short8*)(&As[cur][(wm * 64 + m4 * 16 + col16) * BK + chs * 8]);
            }
#pragma unroll
            for (int n2 = 0; n2 < 2; ++n2) {
                const int chs = (ks * 4 + kg) ^ c8;
                b[n2] = *(const short8*)(&Bs[cur][(wn * 32 + n2 * 16 + col16) * BK + chs * 8]);
            }
#pragma unroll
            for (int m4 = 0; m4 < 4; ++m4)
#pragma unroll
                for (int n2 = 0; n2 < 2; ++n2)
                    acc[m4][n2] = __builtin_amdgcn_mfma_f32_16x16x32_bf16(
                        a[m4], b[n2], acc[m4][n2], 0, 0, 0);
        }

        {
            const int nf = t >> 3, mf = (t >> 1) & 3, rg0 = (t & 1) * 2;
            const int mloc0 = wm * 64 + mf * 16 + kg * 4 + rg0;
            const float4* iv0 = (const float4*)(sInter + mloc0 * 8);
            const float4* iv1 = (const float4*)(sInter + (mloc0 + 1) * 8);
            float4 i00 = iv0[0], i01 = iv0[1], i10 = iv1[0], i11 = iv1[1];
            float4 a00 = areg[cur][0], a01 = areg[cur][1];
            float4 a10 = areg[cur][2], a11 = areg[cur][3];
            float d0 = dot4(a00, i00) + dot4(a01, i01);
            float d1 = dot4(a10, i10) + dot4(a11, i11);
            acc[mf][nf][rg0] += d0;
            acc[mf][nf][rg0 + 1] += d1;
        }

        __builtin_amdgcn_s_barrier();
    }

#pragma unroll
    for (int nf = 0; nf < 2; ++nf) {
        const int oc = wn * 32 + nf * 16 + col16;
        const int o = N0 + oc;
        const float bb = sBias[oc];
#pragma unroll
        for (int mf = 0; mf < 4; ++mf) {
#pragma unroll
            for (int rg = 0; rg < 4; ++rg) {
                const int m = M0 + wm * 64 + mf * 16 + kg * 4 + rg;
                out[(size_t)m * DOUT + o] = acc[mf][nf][rg] + bb;
            }
        }
    }
}

extern "C" void kernel_launch(void* const* d_in, const int* in_sizes, int n_in,
                              void* d_out, int out_size, void* d_ws, size_t ws_size,
                              hipStream_t stream) {
    const float* x    = (const float*)d_in[0];
    const float* Ap   = (const float*)d_in[1];
    const float* Bp   = (const float*)d_in[2];
    const float* W    = (const float*)d_in[3];
    const float* bias = (const float*)d_in[4];
    float* out = (float*)d_out;

    // ws: xb (8 MB) | Wb (2 MB) | inter (128 KB)
    ushort* xb = (ushort*)d_ws;
    ushort* Wb = xb + (size_t)TOKENS * DIN;
    float* inter = (float*)(Wb + (size_t)DOUT * DIN);

    hipLaunchKernelGGL(k_inter_cvt, dim3(2048 + 256), dim3(256), 0, stream,
                       x, Bp, W, inter, xb, Wb);
    hipLaunchKernelGGL(k_gemm_fused, dim3((TOKENS / BM) * (DOUT / BN)), dim3(256), 0, stream,
                       xb, Wb, bias, inter, Ap, out);
}